// Round 17
// baseline (1387.185 us; speedup 1.0000x reference)
//
#include <hip/hip_runtime.h>
#include <hip/hip_bf16.h>

typedef short v8s __attribute__((ext_vector_type(8)));
typedef int   v8i __attribute__((ext_vector_type(8)));
typedef float v4f __attribute__((ext_vector_type(4)));
typedef float v2f __attribute__((ext_vector_type(2)));

#define T_ 512

// HW fp8 (OCP e4m3fn) unpack; word-select must be a literal constant
template<int HI>
__device__ __forceinline__ v2f cvt2(unsigned int wsrc){
  return __builtin_amdgcn_cvt_pk_f32_fp8((int)wsrc, HI);
}
__device__ __forceinline__ v2f rcp2(v2f d){
  return (v2f){__builtin_amdgcn_rcpf(d.x), __builtin_amdgcn_rcpf(d.y)};
}
// packed Pade(3,2) tanh with med3 clamp (2 cells per call)
__device__ __forceinline__ v2f tanh2(v2f x){
  v2f x2 = x*x;
  v2f num = x*(x2 + 27.f);
  v2f den = x2*9.f + 27.f;
  v2f r = num * rcp2(den);
  return (v2f){__builtin_amdgcn_fmed3f(r.x,-1.f,1.f),
               __builtin_amdgcn_fmed3f(r.y,-1.f,1.f)};
}
// sigm(x) = 0.5 + 0.5*tanh_pade(x/2), coefficients folded:
// = 0.5 + x(108+x^2)/(36x^2+432), half-term clamped to +-0.5
__device__ __forceinline__ v2f sigm2(v2f x){
  v2f x2 = x*x;
  v2f num = x*(x2 + 108.f);
  v2f den = x2*36.f + 432.f;
  v2f r = num * rcp2(den);
  v2f rc = (v2f){__builtin_amdgcn_fmed3f(r.x,-0.5f,0.5f),
                 __builtin_amdgcn_fmed3f(r.y,-0.5f,0.5f)};
  return rc + 0.5f;
}
// pi permutation: physical packed position p (0..255) -> logical h column
__device__ __forceinline__ int pi_col(int p){
  return ((p>>5)<<5) + ((p&1)<<4) + ((p&31)>>1);
}
__device__ __forceinline__ v8i ld32(const void* p){
  uint4 lo = *(const uint4*)p;
  uint4 hi = *(const uint4*)((const char*)p + 16);
  v8i r;
  r[0]=(int)lo.x; r[1]=(int)lo.y; r[2]=(int)lo.z; r[3]=(int)lo.w;
  r[4]=(int)hi.x; r[5]=(int)hi.y; r[6]=(int)hi.z; r[7]=(int)hi.w;
  return r;
}
// fp4 e2m1 encode of x (magnitudes {0,.5,1,1.5,2,3,4,6})
__device__ __forceinline__ unsigned f2fp4(float x){
  unsigned s = (x < 0.f) ? 8u : 0u;
  float a = fabsf(x);
  unsigned m;
  if      (a < 0.25f) m=0u; else if (a < 0.75f) m=1u;
  else if (a < 1.25f) m=2u; else if (a < 1.75f) m=3u;
  else if (a < 2.5f ) m=4u; else if (a < 3.5f ) m=5u;
  else if (a < 5.f  ) m=6u; else m=7u;
  return s|m;
}
// f32x4 -> packed fp8 dword
__device__ __forceinline__ unsigned pk8(float a, float b, float c, float d){
  int w = __builtin_amdgcn_cvt_pk_fp8_f32(a, b, 0, 0);
  w     = __builtin_amdgcn_cvt_pk_fp8_f32(c, d, w, 1);
  return (unsigned)w;
}
// branchless fp4 encode of 2 h values (|h|<=1), stored as h*4 (scale 2^-2).
__device__ __forceinline__ unsigned enc4(v2f h){
  v2f t = h*4.f;
  unsigned b = 0;
  #pragma unroll
  for (int s=0;s<2;++s){
    float v = s ? t.y : t.x;
    float ax = __builtin_amdgcn_fmed3f(fabsf(v), 0.f, 4.f);
    float gl = fmaf(ax, 2.f, 12582912.f);   // RNE(ax*2) in low mantissa bits
    float gh = ax + 12582912.f;             // RNE(ax)
    unsigned ql = __builtin_bit_cast(unsigned, gl) & 7u;
    unsigned qh = (__builtin_bit_cast(unsigned, gh) & 7u) + 2u;
    unsigned c  = (ax > 1.75f) ? qh : ql;
    unsigned sg = (__builtin_bit_cast(unsigned, v) >> 28) & 8u;
    b |= (c | sg) << (4*s);
  }
  return b;
}

// Merged prep: blocks 0..63 build fp8 K=128 Wih fragments (both dirs);
// blocks 64..127 build fp4 K=128 Whh fragments (both dirs, x64, pi-permuted).
__global__ __launch_bounds__(256) void prep_k(
    const float* __restrict__ WihA, const float* __restrict__ WihB,
    const float* __restrict__ WhhF, const float* __restrict__ WhhB,
    unsigned char* __restrict__ wih_out, unsigned char* __restrict__ whh_out)
{
  int blk = blockIdx.x;
  if (blk < 64){
    int idx = blk*256 + threadIdx.x;           // 16384 threads
    int lane = idx & 63;
    int t2 = idx >> 6;                         // 0..255
    int ntile = t2 & 127;
    int kt = t2 >> 7;
    int n = ntile*16 + (lane&15);
    const float* W = (n < 1024) ? (WihA + (size_t)n*256) : (WihB + (size_t)(n-1024)*256);
    int k0 = kt*128 + (lane>>4)*32;
    unsigned words[8];
    #pragma unroll
    for (int e=0;e<8;++e)
      words[e] = pk8(W[k0+e*4], W[k0+e*4+1], W[k0+e*4+2], W[k0+e*4+3]);
    unsigned char* d = wih_out + (size_t)idx*32;
    *(uint4*)(d)      = make_uint4(words[0], words[1], words[2], words[3]);
    *(uint4*)(d + 16) = make_uint4(words[4], words[5], words[6], words[7]);
  } else {
    int idx = (blk-64)*256 + threadIdx.x;      // 16384 threads
    int lane = idx & 63;
    int t2 = idx >> 6;                         // 0..255
    int ntile = t2 & 63;
    int kt = (t2>>6) & 1;
    int dir = t2 >> 7;
    const float* W = dir ? WhhB : WhhF;
    int n = ntile*16 + (lane&15);
    int kbase = kt*128 + (lane>>4)*32;
    const float* row = W + (size_t)n*256;
    unsigned words[4];
    #pragma unroll
    for (int d4=0;d4<4;++d4){
      unsigned acc = 0;
      #pragma unroll
      for (int j=0;j<8;++j){
        float v = row[pi_col(kbase + d4*8 + j)] * 64.f;
        acc |= f2fp4(v) << (4*j);
      }
      words[d4] = acc;
    }
    *(uint4*)(whh_out + (size_t)idx*16) = make_uint4(words[0], words[1], words[2], words[3]);
  }
}

// xw = x @ [Wih_f; Wih_b]^T + bias (fp8 MX MFMA, K=128), M=128 rows/block.
__global__ __launch_bounds__(256) void xw_gemm_k(
    const int* __restrict__ sent, const float* __restrict__ emb,
    const unsigned char* __restrict__ wihg, const int* __restrict__ lens,
    const float* __restrict__ bfv, const float* __restrict__ bbv,
    unsigned char* __restrict__ xw)
{
  int mt = blockIdx.x;                         // 0..511, 128 rows each
  if (((mt&3)<<7) >= lens[mt>>2]) return;      // tile fully beyond len
  __shared__ unsigned char A[128][272];        // fp8 x rows
  int tid = threadIdx.x;
  {
    int row = tid>>1, half = tid&1;
    int tok = sent[mt*128 + row];
    const float4* s = (const float4*)(emb + (size_t)tok*256 + half*128);
    unsigned char* drow = &A[row][half*128];
    #pragma unroll
    for (int c4=0; c4<8; ++c4){
      unsigned w0[4];
      #pragma unroll
      for (int u=0; u<4; ++u){
        float4 v = s[c4*4+u];
        w0[u] = pk8(v.x, v.y, v.z, v.w);
      }
      *(uint4*)(drow + c4*16) = make_uint4(w0[0], w0[1], w0[2], w0[3]);
    }
  }
  __syncthreads();
  int w = tid>>6, lane = tid&63, lr = lane&15, lq = lane>>4;
  #pragma unroll 1
  for (int i4=0; i4<4; ++i4){
    int dnv = w*4 + i4;
    int dn = dnv>>3, v = dnv&7;
    const float* bb = dn ? bbv : bfv;
    float bias[8];
    #pragma unroll
    for (int e=0;e<8;++e){
      int q = e>>1, s = e&1;
      bias[e] = bb[q*256 + v*32 + s*16 + lr];
    }
    #pragma unroll 1
    for (int mh=0; mh<2; ++mh){
      v4f acc[8][4];
      #pragma unroll
      for (int e=0;e<8;++e)
        #pragma unroll
        for (int mm=0;mm<4;++mm) acc[e][mm] = (v4f){0.f,0.f,0.f,0.f};
      #pragma unroll
      for (int kt=0;kt<2;++kt){
        v8i a0 = ld32(&A[mh*64 +  0 + lr][kt*128 + lq*32]);
        v8i a1 = ld32(&A[mh*64 + 16 + lr][kt*128 + lq*32]);
        v8i a2 = ld32(&A[mh*64 + 32 + lr][kt*128 + lq*32]);
        v8i a3 = ld32(&A[mh*64 + 48 + lr][kt*128 + lq*32]);
        #pragma unroll
        for (int e=0;e<8;++e){
          int q = e>>1, s = e&1;
          int ntile = dn*64 + q*16 + v*2 + s;
          v8i bfr = ld32(wihg + ((size_t)(kt*128 + ntile)*64 + lane)*32);
          acc[e][0] = __builtin_amdgcn_mfma_scale_f32_16x16x128_f8f6f4(
                        a0, bfr, acc[e][0], 0,0, 0,0x7f7f7f7f, 0,0x7f7f7f7f);
          acc[e][1] = __builtin_amdgcn_mfma_scale_f32_16x16x128_f8f6f4(
                        a1, bfr, acc[e][1], 0,0, 0,0x7f7f7f7f, 0,0x7f7f7f7f);
          acc[e][2] = __builtin_amdgcn_mfma_scale_f32_16x16x128_f8f6f4(
                        a2, bfr, acc[e][2], 0,0, 0,0x7f7f7f7f, 0,0x7f7f7f7f);
          acc[e][3] = __builtin_amdgcn_mfma_scale_f32_16x16x128_f8f6f4(
                        a3, bfr, acc[e][3], 0,0, 0,0x7f7f7f7f, 0,0x7f7f7f7f);
        }
      }
      #pragma unroll
      for (int mm=0;mm<4;++mm){
        #pragma unroll
        for (int j=0;j<4;++j){
          int row = mt*128 + mh*64 + mm*16 + lq*4 + j;
          unsigned lo = pk8(acc[0][mm][j]+bias[0], acc[1][mm][j]+bias[1],
                            acc[2][mm][j]+bias[2], acc[3][mm][j]+bias[3]);
          unsigned hi = pk8(acc[4][mm][j]+bias[4], acc[5][mm][j]+bias[5],
                            acc[6][mm][j]+bias[6], acc[7][mm][j]+bias[7]);
          *(uint2*)(xw + ((size_t)dn*65536 + row)*1024 + v*128 + lr*8)
              = make_uint2(lo, hi);
        }
      }
    }
  }
}

// Recurrence: 32 blocks x 1024 threads; block = 4 seqs x BOTH dirs.
// Waves 0-7 run dir0's chain, waves 8-15 run dir1's chain -- two independent
// chains in SEPARATE waves on one CU, so dir0's VALU epilogue co-schedules
// with dir1's MFMA/loads (m114). One shared barrier serves both chains.
__global__ __launch_bounds__(1024,1) void lstm_k(
    const unsigned char* __restrict__ xw,
    const unsigned char* __restrict__ whh4,
    const int* __restrict__ lens,
    unsigned char* __restrict__ hout)
{
  int grp = blockIdx.x;                        // 0..31: 4 seqs, both dirs
  int tid = threadIdx.x, w = tid>>6, lane = tid&63, lr = lane&15, lq = lane>>4;
  int dirw = w>>3, w8 = w&7;
  __shared__ unsigned char hbuf[2][2][16][136];   // [dbuf][dir][row][col] fp4
  __shared__ int tmax_s;
  for (int i=tid*4; i<2*2*16*136; i+=1024*4)
    *(unsigned int*)(&((unsigned char*)hbuf)[i]) = 0u;
  if (tid==0){
    int mx=0;
    for (int i=0;i<4;++i){ int l = lens[grp*4+i]; mx = l>mx? l:mx; }
    tmax_s = mx;
  }
  // Whh fp4 fragments (padded v8i); this wave's dir only.
  v8i wreg[16];
  const unsigned char* wb = whh4 + (size_t)dirw*131072 + (size_t)lane*16;
  #pragma unroll
  for (int kt=0;kt<2;++kt){
    #pragma unroll
    for (int nt=0;nt<8;++nt){
      int ntile = (nt>>1)*16 + w8*2 + (nt&1);
      uint4 t = *(const uint4*)(wb + (size_t)(kt*64 + ntile)*1024);
      v8i r;
      r[0]=(int)t.x; r[1]=(int)t.y; r[2]=(int)t.z; r[3]=(int)t.w;
      r[4]=0; r[5]=0; r[6]=0; r[7]=0;
      wreg[kt*8+nt] = r;
    }
  }
  int seq = grp*4 + lq;
  int ln = lens[seq];
  v2f cc = (v2f){0.f, 0.f};
  const size_t dbase = (size_t)dirw*65536;
  const unsigned char* xbase = xw + (dbase + (size_t)seq*T_)*1024 + w8*128 + lr*8;
  unsigned char* hbase = hout + (dbase + (size_t)seq*T_)*256 + w8*32 + lr*2;
  unsigned char* lw0 = &hbuf[1][dirw][lq*4][w8*16 + lr];  // write when cur=0
  unsigned char* lw1 = &hbuf[0][dirw][lq*4][w8*16 + lr];
  const unsigned char* lr0 = &hbuf[0][dirw][lr][lq*16];   // read when cur=0
  const unsigned char* lr1 = &hbuf[1][dirw][lr][lq*16];
  __syncthreads();
  int tmax = tmax_s;
  uint2 xv = *(const uint2*)(xbase + (size_t)(dirw ? (ln-1) : 0)*1024);
  for (int t=0; t<tmax; ++t){
    int cur = t&1;
    int tn = (t+1<tmax)? t+1 : t;
    int te = dirw ? ((tn<ln)? (ln-1-tn) : tn) : tn;     // wave-uniform branch
    uint2 xn = *(const uint2*)(xbase + ((size_t)te<<10));
    const unsigned char* lrd = cur? lr1 : lr0;
    v2f xi = cvt2<0>(xv.x), xf = cvt2<1>(xv.x);
    v2f xg = cvt2<0>(xv.y), xo = cvt2<1>(xv.y);
    v4f acc[8];
    #pragma unroll
    for (int nt=0;nt<8;++nt) asm("" : "=v"(acc[nt]));
    acc[0][0] = xi.x; acc[1][0] = xi.y;
    acc[2][0] = xf.x; acc[3][0] = xf.y;
    acc[4][0] = xg.x; acc[5][0] = xg.y;
    acc[6][0] = xo.x; acc[7][0] = xo.y;
    #pragma unroll
    for (int kt=0;kt<2;++kt){
      uint4 hh = *(const uint4*)(lrd + kt*64);
      v8i a;
      a[0]=(int)hh.x; a[1]=(int)hh.y; a[2]=(int)hh.z; a[3]=(int)hh.w;
      a[4]=0; a[5]=0; a[6]=0; a[7]=0;
      #pragma unroll
      for (int nt=0;nt<8;++nt)
        acc[nt] = __builtin_amdgcn_mfma_scale_f32_16x16x128_f8f6f4(
                    a, wreg[kt*8+nt], acc[nt], 4, 4,
                    0, 0x7D7D7D7D, 0, 0x79797979);
    }
    int pos = dirw ? ((t<ln)? (ln-1-t) : t) : t;
    v2f gi = (v2f){acc[0][0], acc[1][0]};
    v2f gf = (v2f){acc[2][0], acc[3][0]};
    v2f gg = (v2f){acc[4][0], acc[5][0]};
    v2f go = (v2f){acc[6][0], acc[7][0]};
    v2f iv = sigm2(gi), fv = sigm2(gf), gv = tanh2(gg), ov = sigm2(go);
    v2f cn = fv*cc + iv*gv;
    v2f hn = ov*tanh2(cn);
    cc = cn;
    *(cur? lw1 : lw0) = (unsigned char)enc4(hn);
    int hp = __builtin_amdgcn_cvt_pk_fp8_f32(hn.x, hn.y, 0, 0);
    *(unsigned short*)(hbase + ((size_t)pos<<8)) = (unsigned short)(hp&0xffff);
    xv = xn;
    asm volatile("s_waitcnt lgkmcnt(0)" ::: "memory");
    __builtin_amdgcn_s_barrier();
    __builtin_amdgcn_sched_barrier(0);
  }
}

// em = [h_f, h_b] @ Wout^T + b_out. Coalesced: 16-lane group per 256B row.
__global__ __launch_bounds__(256) void em_k(
    const unsigned char* __restrict__ hout,
    const float* __restrict__ Wout, const float* __restrict__ bout,
    const int* __restrict__ lens,
    float* __restrict__ em)
{
  __shared__ float Ws[9*512];
  for (int i=threadIdx.x;i<9*512;i+=256){
    int k = i>>9, p = i&511;
    int d = p>>8, pp = p&255;
    Ws[i] = Wout[k*512 + d*256 + pi_col(pp)];
  }
  __syncthreads();
  int wv = blockIdx.x*4 + (threadIdx.x>>6);
  int lane = threadIdx.x & 63;
  int g = lane>>4, r = lane&15;
  int m = wv*4 + g;
  const unsigned char* hf = hout + (size_t)m*256 + r*16;
  const unsigned char* hb = hout + ((size_t)65536 + m)*256 + r*16;
  uint4 vf = *(const uint4*)hf;
  uint4 vb = *(const uint4*)hb;
  float xf[16], xb[16];
  {
    v2f d0=cvt2<0>(vf.x), d1=cvt2<1>(vf.x), d2=cvt2<0>(vf.y), d3=cvt2<1>(vf.y);
    v2f d4=cvt2<0>(vf.z), d5=cvt2<1>(vf.z), d6=cvt2<0>(vf.w), d7=cvt2<1>(vf.w);
    xf[0]=d0.x; xf[1]=d0.y; xf[2]=d1.x; xf[3]=d1.y;
    xf[4]=d2.x; xf[5]=d2.y; xf[6]=d3.x; xf[7]=d3.y;
    xf[8]=d4.x; xf[9]=d4.y; xf[10]=d5.x; xf[11]=d5.y;
    xf[12]=d6.x; xf[13]=d6.y; xf[14]=d7.x; xf[15]=d7.y;
  }
  {
    v2f d0=cvt2<0>(vb.x), d1=cvt2<1>(vb.x), d2=cvt2<0>(vb.y), d3=cvt2<1>(vb.y);
    v2f d4=cvt2<0>(vb.z), d5=cvt2<1>(vb.z), d6=cvt2<0>(vb.w), d7=cvt2<1>(vb.w);
    xb[0]=d0.x; xb[1]=d0.y; xb[2]=d1.x; xb[3]=d1.y;
    xb[4]=d2.x; xb[5]=d2.y; xb[6]=d3.x; xb[7]=d3.y;
    xb[8]=d4.x; xb[9]=d4.y; xb[10]=d5.x; xb[11]=d5.y;
    xb[12]=d6.x; xb[13]=d6.y; xb[14]=d7.x; xb[15]=d7.y;
  }
  float a[9];
  #pragma unroll
  for (int k=0;k<9;++k){
    float s = 0.f;
    #pragma unroll
    for (int e=0;e<16;++e)
      s += xf[e]*Ws[k*512 + r*16 + e] + xb[e]*Ws[k*512 + 256 + r*16 + e];
    a[k]=s;
  }
  #pragma unroll
  for (int k=0;k<9;++k){
    #pragma unroll
    for (int off=8; off; off>>=1) a[k] += __shfl_xor(a[k], off, 64);
  }
  int b = m>>9, t = m&511;
  if (r==0 && t < lens[b]){
    float* d = em + (size_t)m*9;
    #pragma unroll
    for (int k=0;k<9;++k) d[k] = a[k] + bout[k];
  }
}

// CRF: one wave per sequence.
__global__ __launch_bounds__(256) void crf_k(
    const float* __restrict__ em, const int* __restrict__ tags,
    const int* __restrict__ lens, const float* __restrict__ startv,
    const float* __restrict__ endv, const float* __restrict__ trans,
    float* __restrict__ out)
{
  int wid = blockIdx.x*4 + (threadIdx.x>>6);
  int lane = threadIdx.x & 63;
  const float* e = em + (size_t)wid*T_*9;
  const int* tg = tags + (size_t)wid*T_;
  int L = lens[wid];
  float p = 0.f;
  for (int t = 1+lane; t < L; t += 64)
    p += trans[tg[t-1]*9 + tg[t]] + e[(size_t)t*9 + tg[t]];
  if (lane==0) p += startv[tg[0]] + e[tg[0]] + endv[tg[L-1]];
  #pragma unroll
  for (int off=32; off; off>>=1) p += __shfl_xor(p, off, 64);
  float tcol[9];
  #pragma unroll
  for (int i=0;i<9;++i) tcol[i] = (lane<9) ? trans[i*9 + lane] : 0.f;
  float alpha = (lane<9) ? (startv[lane] + e[lane]) : -1e30f;
  for (int t=1; t<L; ++t){
    float vs[9]; float mx = -1e30f;
    #pragma unroll
    for (int i=0;i<9;++i){
      float ai = __shfl(alpha, i, 64);
      vs[i] = ai + tcol[i];
      mx = fmaxf(mx, vs[i]);
    }
    float s = 0.f;
    #pragma unroll
    for (int i=0;i<9;++i) s += __expf(vs[i]-mx);
    float na = mx + __logf(s) + ((lane<9)? e[(size_t)t*9+lane] : 0.f);
    alpha = (lane<9) ? na : -1e30f;
  }
  float v = (lane<9) ? (alpha + endv[lane]) : -1e30f;
  float mx = v;
  #pragma unroll
  for (int off=32; off; off>>=1) mx = fmaxf(mx, __shfl_xor(mx, off, 64));
  float s = __expf(v-mx);
  #pragma unroll
  for (int off=32; off; off>>=1) s += __shfl_xor(s, off, 64);
  float logZ = mx + __logf(s);
  if (lane==0) atomicAdd(out, p - logZ);
}

extern "C" void kernel_launch(void* const* d_in, const int* in_sizes, int n_in,
                              void* d_out, int out_size, void* d_ws, size_t ws_size,
                              hipStream_t stream)
{
  const int*   sent  = (const int*)d_in[0];
  const int*   tags  = (const int*)d_in[1];
  const int*   lens  = (const int*)d_in[2];
  const float* emb   = (const float*)d_in[3];
  const float* Wih_f = (const float*)d_in[4];
  const float* Whh_f = (const float*)d_in[5];
  const float* b_f   = (const float*)d_in[6];
  const float* Wih_b = (const float*)d_in[7];
  const float* Whh_b = (const float*)d_in[8];
  const float* b_b   = (const float*)d_in[9];
  const float* Wout  = (const float*)d_in[10];
  const float* bout  = (const float*)d_in[11];
  const float* startv= (const float*)d_in[12];
  const float* endv  = (const float*)d_in[13];
  const float* trans = (const float*)d_in[14];
  char* ws = (char*)d_ws;
  // layout (~171 MB): wihg8 0.5MB | whh4 0.25MB | xw 128MB | hout 32MB | em 2.25MB
  unsigned char* wihg8 = (unsigned char*)(ws);
  unsigned char* whh4  = (unsigned char*)(ws + (size_t)524288);
  unsigned char* xw    = (unsigned char*)(ws + (size_t)1048576);
  unsigned char* hout  = (unsigned char*)(ws + (size_t)135266304);
  float* em            = (float*)(ws + (size_t)168820736);
  float* outp = (float*)d_out;

  (void)hipMemsetAsync(outp, 0, sizeof(float), stream);
  prep_k<<<128, 256, 0, stream>>>(Wih_f, Wih_b, Whh_f, Whh_b, wihg8, whh4);
  xw_gemm_k<<<512, 256, 0, stream>>>(sent, emb, wihg8, lens, b_f, b_b, xw);
  lstm_k<<<32, 1024, 0, stream>>>(xw, whh4, lens, hout);
  em_k<<<4096, 256, 0, stream>>>(hout, Wout, bout, lens, em);
  crf_k<<<32, 256, 0, stream>>>(em, tags, lens, startv, endv, trans, outp);
}

// Round 18
// 697.001 us; speedup vs baseline: 1.9902x; 1.9902x over previous
//
#include <hip/hip_runtime.h>
#include <hip/hip_bf16.h>

typedef short v8s __attribute__((ext_vector_type(8)));
typedef int   v8i __attribute__((ext_vector_type(8)));
typedef float v4f __attribute__((ext_vector_type(4)));
typedef float v2f __attribute__((ext_vector_type(2)));

#define T_ 512

// HW fp8 (OCP e4m3fn) unpack; word-select must be a literal constant
template<int HI>
__device__ __forceinline__ v2f cvt2(unsigned int wsrc){
  return __builtin_amdgcn_cvt_pk_f32_fp8((int)wsrc, HI);
}
__device__ __forceinline__ v2f rcp2(v2f d){
  return (v2f){__builtin_amdgcn_rcpf(d.x), __builtin_amdgcn_rcpf(d.y)};
}
// packed Pade(3,2) tanh with med3 clamp (2 values per call)
__device__ __forceinline__ v2f tanh2(v2f x){
  v2f x2 = x*x;
  v2f num = x*(x2 + 27.f);
  v2f den = x2*9.f + 27.f;
  v2f r = num * rcp2(den);
  return (v2f){__builtin_amdgcn_fmed3f(r.x,-1.f,1.f),
               __builtin_amdgcn_fmed3f(r.y,-1.f,1.f)};
}
__device__ __forceinline__ v2f sigm2(v2f x){
  v2f y = x*0.5f;
  v2f y2 = y*y;
  v2f num = y*(y2 + 27.f);
  v2f den = y2*9.f + 27.f;
  v2f r = num * rcp2(den);
  v2f rc = (v2f){__builtin_amdgcn_fmed3f(r.x,-1.f,1.f),
                 __builtin_amdgcn_fmed3f(r.y,-1.f,1.f)};
  return rc*0.5f + 0.5f;
}
// scalar variants (per-cell split epilogue)
__device__ __forceinline__ float tanh1(float x){
  float x2 = x*x;
  float r = (x*(27.f + x2)) * __builtin_amdgcn_rcpf(27.f + 9.f*x2);
  return __builtin_amdgcn_fmed3f(r, -1.f, 1.f);
}
__device__ __forceinline__ float sigm1(float x){
  return 0.5f + 0.5f*tanh1(0.5f*x);
}
// pi permutation: physical packed position p (0..255) -> logical h column
__device__ __forceinline__ int pi_col(int p){
  return ((p>>5)<<5) + ((p&1)<<4) + ((p&31)>>1);
}
__device__ __forceinline__ v8i ld32(const void* p){
  uint4 lo = *(const uint4*)p;
  uint4 hi = *(const uint4*)((const char*)p + 16);
  v8i r;
  r[0]=(int)lo.x; r[1]=(int)lo.y; r[2]=(int)lo.z; r[3]=(int)lo.w;
  r[4]=(int)hi.x; r[5]=(int)hi.y; r[6]=(int)hi.z; r[7]=(int)hi.w;
  return r;
}
// fp4 e2m1 encode of x (magnitudes {0,.5,1,1.5,2,3,4,6})
__device__ __forceinline__ unsigned f2fp4(float x){
  unsigned s = (x < 0.f) ? 8u : 0u;
  float a = fabsf(x);
  unsigned m;
  if      (a < 0.25f) m=0u; else if (a < 0.75f) m=1u;
  else if (a < 1.25f) m=2u; else if (a < 1.75f) m=3u;
  else if (a < 2.5f ) m=4u; else if (a < 3.5f ) m=5u;
  else if (a < 5.f  ) m=6u; else m=7u;
  return s|m;
}
// f32x4 -> packed fp8 dword
__device__ __forceinline__ unsigned pk8(float a, float b, float c, float d){
  int w = __builtin_amdgcn_cvt_pk_fp8_f32(a, b, 0, 0);
  w     = __builtin_amdgcn_cvt_pk_fp8_f32(c, d, w, 1);
  return (unsigned)w;
}
// branchless fp4 encode of one h value (|h|<=1), stored as h*4 (scale 2^-2)
__device__ __forceinline__ unsigned enc4s(float v4x){
  float ax = __builtin_amdgcn_fmed3f(fabsf(v4x), 0.f, 4.f);
  float gl = fmaf(ax, 2.f, 12582912.f);   // RNE(ax*2) in low mantissa bits
  float gh = ax + 12582912.f;             // RNE(ax)
  unsigned ql = __builtin_bit_cast(unsigned, gl) & 7u;
  unsigned qh = (__builtin_bit_cast(unsigned, gh) & 7u) + 2u;
  unsigned c  = (ax > 1.75f) ? qh : ql;
  unsigned sg = (__builtin_bit_cast(unsigned, v4x) >> 28) & 8u;
  return c | sg;
}

// Merged prep: blocks 0..63 build fp8 K=128 Wih fragments (both dirs);
// blocks 64..127 build fp4 K=128 Whh fragments (both dirs, x64, pi-permuted).
__global__ __launch_bounds__(256) void prep_k(
    const float* __restrict__ WihA, const float* __restrict__ WihB,
    const float* __restrict__ WhhF, const float* __restrict__ WhhB,
    unsigned char* __restrict__ wih_out, unsigned char* __restrict__ whh_out)
{
  int blk = blockIdx.x;
  if (blk < 64){
    int idx = blk*256 + threadIdx.x;           // 16384 threads
    int lane = idx & 63;
    int t2 = idx >> 6;                         // 0..255
    int ntile = t2 & 127;
    int kt = t2 >> 7;
    int n = ntile*16 + (lane&15);
    const float* W = (n < 1024) ? (WihA + (size_t)n*256) : (WihB + (size_t)(n-1024)*256);
    int k0 = kt*128 + (lane>>4)*32;
    unsigned words[8];
    #pragma unroll
    for (int e=0;e<8;++e)
      words[e] = pk8(W[k0+e*4], W[k0+e*4+1], W[k0+e*4+2], W[k0+e*4+3]);
    unsigned char* d = wih_out + (size_t)idx*32;
    *(uint4*)(d)      = make_uint4(words[0], words[1], words[2], words[3]);
    *(uint4*)(d + 16) = make_uint4(words[4], words[5], words[6], words[7]);
  } else {
    int idx = (blk-64)*256 + threadIdx.x;      // 16384 threads
    int lane = idx & 63;
    int t2 = idx >> 6;                         // 0..255
    int ntile = t2 & 63;
    int kt = (t2>>6) & 1;
    int dir = t2 >> 7;
    const float* W = dir ? WhhB : WhhF;
    int n = ntile*16 + (lane&15);
    int kbase = kt*128 + (lane>>4)*32;
    const float* row = W + (size_t)n*256;
    unsigned words[4];
    #pragma unroll
    for (int d4=0;d4<4;++d4){
      unsigned acc = 0;
      #pragma unroll
      for (int j=0;j<8;++j){
        float v = row[pi_col(kbase + d4*8 + j)] * 64.f;
        acc |= f2fp4(v) << (4*j);
      }
      words[d4] = acc;
    }
    *(uint4*)(whh_out + (size_t)idx*16) = make_uint4(words[0], words[1], words[2], words[3]);
  }
}

// xw = x @ [Wih_f; Wih_b]^T + bias (fp8 MX MFMA, K=128), M=128 rows/block.
__global__ __launch_bounds__(256) void xw_gemm_k(
    const int* __restrict__ sent, const float* __restrict__ emb,
    const unsigned char* __restrict__ wihg, const int* __restrict__ lens,
    const float* __restrict__ bfv, const float* __restrict__ bbv,
    unsigned char* __restrict__ xw)
{
  int mt = blockIdx.x;                         // 0..511, 128 rows each
  if (((mt&3)<<7) >= lens[mt>>2]) return;      // tile fully beyond len
  __shared__ unsigned char A[128][272];        // fp8 x rows
  int tid = threadIdx.x;
  {
    int row = tid>>1, half = tid&1;
    int tok = sent[mt*128 + row];
    const float4* s = (const float4*)(emb + (size_t)tok*256 + half*128);
    unsigned char* drow = &A[row][half*128];
    #pragma unroll
    for (int c4=0; c4<8; ++c4){
      unsigned w0[4];
      #pragma unroll
      for (int u=0; u<4; ++u){
        float4 v = s[c4*4+u];
        w0[u] = pk8(v.x, v.y, v.z, v.w);
      }
      *(uint4*)(drow + c4*16) = make_uint4(w0[0], w0[1], w0[2], w0[3]);
    }
  }
  __syncthreads();
  int w = tid>>6, lane = tid&63, lr = lane&15, lq = lane>>4;
  #pragma unroll 1
  for (int i4=0; i4<4; ++i4){
    int dnv = w*4 + i4;
    int dn = dnv>>3, v = dnv&7;
    const float* bb = dn ? bbv : bfv;
    float bias[8];
    #pragma unroll
    for (int e=0;e<8;++e){
      int q = e>>1, s = e&1;
      bias[e] = bb[q*256 + v*32 + s*16 + lr];
    }
    #pragma unroll 1
    for (int mh=0; mh<2; ++mh){
      v4f acc[8][4];
      #pragma unroll
      for (int e=0;e<8;++e)
        #pragma unroll
        for (int mm=0;mm<4;++mm) acc[e][mm] = (v4f){0.f,0.f,0.f,0.f};
      #pragma unroll
      for (int kt=0;kt<2;++kt){
        v8i a0 = ld32(&A[mh*64 +  0 + lr][kt*128 + lq*32]);
        v8i a1 = ld32(&A[mh*64 + 16 + lr][kt*128 + lq*32]);
        v8i a2 = ld32(&A[mh*64 + 32 + lr][kt*128 + lq*32]);
        v8i a3 = ld32(&A[mh*64 + 48 + lr][kt*128 + lq*32]);
        #pragma unroll
        for (int e=0;e<8;++e){
          int q = e>>1, s = e&1;
          int ntile = dn*64 + q*16 + v*2 + s;
          v8i bfr = ld32(wihg + ((size_t)(kt*128 + ntile)*64 + lane)*32);
          acc[e][0] = __builtin_amdgcn_mfma_scale_f32_16x16x128_f8f6f4(
                        a0, bfr, acc[e][0], 0,0, 0,0x7f7f7f7f, 0,0x7f7f7f7f);
          acc[e][1] = __builtin_amdgcn_mfma_scale_f32_16x16x128_f8f6f4(
                        a1, bfr, acc[e][1], 0,0, 0,0x7f7f7f7f, 0,0x7f7f7f7f);
          acc[e][2] = __builtin_amdgcn_mfma_scale_f32_16x16x128_f8f6f4(
                        a2, bfr, acc[e][2], 0,0, 0,0x7f7f7f7f, 0,0x7f7f7f7f);
          acc[e][3] = __builtin_amdgcn_mfma_scale_f32_16x16x128_f8f6f4(
                        a3, bfr, acc[e][3], 0,0, 0,0x7f7f7f7f, 0,0x7f7f7f7f);
        }
      }
      #pragma unroll
      for (int mm=0;mm<4;++mm){
        #pragma unroll
        for (int j=0;j<4;++j){
          int row = mt*128 + mh*64 + mm*16 + lq*4 + j;
          unsigned lo = pk8(acc[0][mm][j]+bias[0], acc[1][mm][j]+bias[1],
                            acc[2][mm][j]+bias[2], acc[3][mm][j]+bias[3]);
          unsigned hi = pk8(acc[4][mm][j]+bias[4], acc[5][mm][j]+bias[5],
                            acc[6][mm][j]+bias[6], acc[7][mm][j]+bias[7]);
          *(uint2*)(xw + ((size_t)dn*65536 + row)*1024 + v*128 + lr*8)
              = make_uint2(lo, hi);
        }
      }
    }
  }
}

// Recurrence: 64 blocks x 512 threads (R14 structure, best known 448us);
// block = (dir, 4 seqs at A-rows {0,4,8,12}). FULL-fp4 MFMA. Split epilogue:
// even-nt MFMAs (cell 0) first, cell-0 epilogue issues UNDER odd-nt MFMAs.
__global__ __launch_bounds__(512,1) void lstm_k(
    const unsigned char* __restrict__ xw,
    const unsigned char* __restrict__ whh4,
    const int* __restrict__ lens,
    unsigned char* __restrict__ hout)
{
  int bid = blockIdx.x, dir = bid>>5, grp = bid&31;
  int tid = threadIdx.x, w = tid>>6, lane = tid&63, lr = lane&15, lq = lane>>4;
  __shared__ unsigned char hbuf[2][16][136];   // fp4 h: 128B data + pad
  __shared__ int tmax_s;
  for (int i=tid*4; i<2*16*136; i+=512*4) *(unsigned int*)(&((unsigned char*)hbuf)[i]) = 0u;
  if (tid==0){
    int mx=0;
    for (int i=0;i<4;++i){ int l = lens[grp*4+i]; mx = l>mx? l:mx; }
    tmax_s = mx;
  }
  v8i wreg[16];
  const unsigned char* wb = whh4 + (size_t)dir*131072;
  #pragma unroll
  for (int kt=0;kt<2;++kt){
    #pragma unroll
    for (int nt=0;nt<8;++nt){
      int ntile = (nt>>1)*16 + w*2 + (nt&1);
      uint4 t = *(const uint4*)(wb + ((size_t)(kt*64 + ntile)*64 + lane)*16);
      v8i r;
      r[0]=(int)t.x; r[1]=(int)t.y; r[2]=(int)t.z; r[3]=(int)t.w;
      r[4]=0; r[5]=0; r[6]=0; r[7]=0;
      wreg[kt*8+nt] = r;
    }
  }
  int seq = grp*4 + lq;
  int ln = lens[seq];
  float c0 = 0.f, c1 = 0.f;
  const size_t dbase = (size_t)dir*65536;
  const unsigned char* xbase = xw + (dbase + (size_t)seq*T_)*1024 + w*128 + lr*8;
  unsigned char* hbase = hout + (dbase + (size_t)seq*T_)*256 + w*32 + lr*2;
  unsigned char* lw0 = &hbuf[1][lq*4][w*16 + lr];   // write target when cur=0
  unsigned char* lw1 = &hbuf[0][lq*4][w*16 + lr];
  const unsigned char* lr0 = &hbuf[0][lr][lq*16];   // read source when cur=0
  const unsigned char* lr1 = &hbuf[1][lr][lq*16];
  __syncthreads();
  int tmax = tmax_s;
  uint2 xv = *(const uint2*)(xbase + (size_t)(dir ? (ln-1) : 0)*1024);

  #define STEP_BODY(TE_EXPR, POS_EXPR)                                         \
    int cur = t&1;                                                             \
    int tn = (t+1<tmax)? t+1 : t;                                              \
    int te = (TE_EXPR);                                                        \
    uint2 xn = *(const uint2*)(xbase + ((size_t)te<<10));                      \
    const unsigned char* lrd = cur? lr1 : lr0;                                 \
    v2f xi = cvt2<0>(xv.x), xf = cvt2<1>(xv.x);                                \
    v2f xg = cvt2<0>(xv.y), xo = cvt2<1>(xv.y);                                \
    v4f acc[8];                                                                \
    _Pragma("unroll")                                                          \
    for (int nt=0;nt<8;++nt) asm("" : "=v"(acc[nt]));                          \
    acc[0][0] = xi.x; acc[1][0] = xi.y;                                        \
    acc[2][0] = xf.x; acc[3][0] = xf.y;                                        \
    acc[4][0] = xg.x; acc[5][0] = xg.y;                                        \
    acc[6][0] = xo.x; acc[7][0] = xo.y;                                        \
    uint4 hh0 = *(const uint4*)(lrd);                                          \
    uint4 hh1 = *(const uint4*)(lrd + 64);                                     \
    v8i a0;                                                                    \
    a0[0]=(int)hh0.x; a0[1]=(int)hh0.y; a0[2]=(int)hh0.z; a0[3]=(int)hh0.w;    \
    a0[4]=0; a0[5]=0; a0[6]=0; a0[7]=0;                                        \
    v8i a1;                                                                    \
    a1[0]=(int)hh1.x; a1[1]=(int)hh1.y; a1[2]=(int)hh1.z; a1[3]=(int)hh1.w;    \
    a1[4]=0; a1[5]=0; a1[6]=0; a1[7]=0;                                        \
    /* cell-0 gates (even nt), both kt */                                      \
    _Pragma("unroll")                                                          \
    for (int nt=0;nt<8;nt+=2){                                                 \
      acc[nt] = __builtin_amdgcn_mfma_scale_f32_16x16x128_f8f6f4(              \
                  a0, wreg[nt], acc[nt], 4, 4, 0, 0x7D7D7D7D, 0, 0x79797979);  \
      acc[nt] = __builtin_amdgcn_mfma_scale_f32_16x16x128_f8f6f4(              \
                  a1, wreg[8+nt], acc[nt], 4, 4, 0, 0x7D7D7D7D, 0, 0x79797979);\
    }                                                                          \
    /* cell-1 gates (odd nt) issue; cell-0 epilogue overlaps them */           \
    _Pragma("unroll")                                                          \
    for (int nt=1;nt<8;nt+=2){                                                 \
      acc[nt] = __builtin_amdgcn_mfma_scale_f32_16x16x128_f8f6f4(              \
                  a0, wreg[nt], acc[nt], 4, 4, 0, 0x7D7D7D7D, 0, 0x79797979);  \
      acc[nt] = __builtin_amdgcn_mfma_scale_f32_16x16x128_f8f6f4(              \
                  a1, wreg[8+nt], acc[nt], 4, 4, 0, 0x7D7D7D7D, 0, 0x79797979);\
    }                                                                          \
    float iv0 = sigm1(acc[0][0]), fv0 = sigm1(acc[2][0]);                      \
    float gv0 = tanh1(acc[4][0]), ov0 = sigm1(acc[6][0]);                      \
    float cn0 = fv0*c0 + iv0*gv0;                                              \
    float hn0 = ov0*tanh1(cn0);                                                \
    c0 = cn0;                                                                  \
    unsigned e0 = enc4s(hn0*4.f);                                              \
    float iv1 = sigm1(acc[1][0]), fv1 = sigm1(acc[3][0]);                      \
    float gv1 = tanh1(acc[5][0]), ov1 = sigm1(acc[7][0]);                      \
    float cn1 = fv1*c1 + iv1*gv1;                                              \
    float hn1 = ov1*tanh1(cn1);                                                \
    c1 = cn1;                                                                  \
    unsigned e1 = enc4s(hn1*4.f);                                              \
    int pos = (POS_EXPR);                                                      \
    *(cur? lw1 : lw0) = (unsigned char)(e0 | (e1<<4));                         \
    int hp = __builtin_amdgcn_cvt_pk_fp8_f32(hn0, hn1, 0, 0);                  \
    *(unsigned short*)(hbase + ((size_t)pos<<8)) = (unsigned short)(hp&0xffff);\
    xv = xn;                                                                   \
    asm volatile("s_waitcnt lgkmcnt(0)" ::: "memory");                         \
    __builtin_amdgcn_s_barrier();                                              \
    __builtin_amdgcn_sched_barrier(0);

  if (dir == 0){
    for (int t=0; t<tmax; ++t){
      STEP_BODY(tn, t)
    }
  } else {
    for (int t=0; t<tmax; ++t){
      STEP_BODY((tn<ln)? (ln-1-tn) : tn, (t<ln)? (ln-1-t) : t)
    }
  }
  #undef STEP_BODY
}

// em = [h_f, h_b] @ Wout^T + b_out. Coalesced: 16-lane group per 256B row.
// Wave early-exit when all 4 of its rows are beyond len (~50% of waves).
__global__ __launch_bounds__(256) void em_k(
    const unsigned char* __restrict__ hout,
    const float* __restrict__ Wout, const float* __restrict__ bout,
    const int* __restrict__ lens,
    float* __restrict__ em)
{
  __shared__ float Ws[9*512];
  for (int i=threadIdx.x;i<9*512;i+=256){
    int k = i>>9, p = i&511;
    int d = p>>8, pp = p&255;
    Ws[i] = Wout[k*512 + d*256 + pi_col(pp)];
  }
  __syncthreads();
  int wv = blockIdx.x*4 + (threadIdx.x>>6);
  int lane = threadIdx.x & 63;
  int g = lane>>4, r = lane&15;
  int m4 = wv*4;
  int b = m4>>9, t0 = m4&511;
  int len = lens[b];
  if (t0 >= len) return;                       // whole wave beyond len
  int m = m4 + g;
  const unsigned char* hf = hout + (size_t)m*256 + r*16;
  const unsigned char* hb = hout + ((size_t)65536 + m)*256 + r*16;
  uint4 vf = *(const uint4*)hf;
  uint4 vb = *(const uint4*)hb;
  float xf[16], xb[16];
  {
    v2f d0=cvt2<0>(vf.x), d1=cvt2<1>(vf.x), d2=cvt2<0>(vf.y), d3=cvt2<1>(vf.y);
    v2f d4=cvt2<0>(vf.z), d5=cvt2<1>(vf.z), d6=cvt2<0>(vf.w), d7=cvt2<1>(vf.w);
    xf[0]=d0.x; xf[1]=d0.y; xf[2]=d1.x; xf[3]=d1.y;
    xf[4]=d2.x; xf[5]=d2.y; xf[6]=d3.x; xf[7]=d3.y;
    xf[8]=d4.x; xf[9]=d4.y; xf[10]=d5.x; xf[11]=d5.y;
    xf[12]=d6.x; xf[13]=d6.y; xf[14]=d7.x; xf[15]=d7.y;
  }
  {
    v2f d0=cvt2<0>(vb.x), d1=cvt2<1>(vb.x), d2=cvt2<0>(vb.y), d3=cvt2<1>(vb.y);
    v2f d4=cvt2<0>(vb.z), d5=cvt2<1>(vb.z), d6=cvt2<0>(vb.w), d7=cvt2<1>(vb.w);
    xb[0]=d0.x; xb[1]=d0.y; xb[2]=d1.x; xb[3]=d1.y;
    xb[4]=d2.x; xb[5]=d2.y; xb[6]=d3.x; xb[7]=d3.y;
    xb[8]=d4.x; xb[9]=d4.y; xb[10]=d5.x; xb[11]=d5.y;
    xb[12]=d6.x; xb[13]=d6.y; xb[14]=d7.x; xb[15]=d7.y;
  }
  float a[9];
  #pragma unroll
  for (int k=0;k<9;++k){
    float s = 0.f;
    #pragma unroll
    for (int e=0;e<16;++e)
      s += xf[e]*Ws[k*512 + r*16 + e] + xb[e]*Ws[k*512 + 256 + r*16 + e];
    a[k]=s;
  }
  #pragma unroll
  for (int k=0;k<9;++k){
    #pragma unroll
    for (int off=8; off; off>>=1) a[k] += __shfl_xor(a[k], off, 64);
  }
  int t = m&511;
  if (r==0 && t < len){
    float* d = em + (size_t)m*9;
    #pragma unroll
    for (int k=0;k<9;++k) d[k] = a[k] + bout[k];
  }
}

// CRF: one wave per sequence.
__global__ __launch_bounds__(256) void crf_k(
    const float* __restrict__ em, const int* __restrict__ tags,
    const int* __restrict__ lens, const float* __restrict__ startv,
    const float* __restrict__ endv, const float* __restrict__ trans,
    float* __restrict__ out)
{
  int wid = blockIdx.x*4 + (threadIdx.x>>6);
  int lane = threadIdx.x & 63;
  const float* e = em + (size_t)wid*T_*9;
  const int* tg = tags + (size_t)wid*T_;
  int L = lens[wid];
  float p = 0.f;
  for (int t = 1+lane; t < L; t += 64)
    p += trans[tg[t-1]*9 + tg[t]] + e[(size_t)t*9 + tg[t]];
  if (lane==0) p += startv[tg[0]] + e[tg[0]] + endv[tg[L-1]];
  #pragma unroll
  for (int off=32; off; off>>=1) p += __shfl_xor(p, off, 64);
  float tcol[9];
  #pragma unroll
  for (int i=0;i<9;++i) tcol[i] = (lane<9) ? trans[i*9 + lane] : 0.f;
  float alpha = (lane<9) ? (startv[lane] + e[lane]) : -1e30f;
  for (int t=1; t<L; ++t){
    float vs[9]; float mx = -1e30f;
    #pragma unroll
    for (int i=0;i<9;++i){
      float ai = __shfl(alpha, i, 64);
      vs[i] = ai + tcol[i];
      mx = fmaxf(mx, vs[i]);
    }
    float s = 0.f;
    #pragma unroll
    for (int i=0;i<9;++i) s += __expf(vs[i]-mx);
    float na = mx + __logf(s) + ((lane<9)? e[(size_t)t*9+lane] : 0.f);
    alpha = (lane<9) ? na : -1e30f;
  }
  float v = (lane<9) ? (alpha + endv[lane]) : -1e30f;
  float mx = v;
  #pragma unroll
  for (int off=32; off; off>>=1) mx = fmaxf(mx, __shfl_xor(mx, off, 64));
  float s = __expf(v-mx);
  #pragma unroll
  for (int off=32; off; off>>=1) s += __shfl_xor(s, off, 64);
  float logZ = mx + __logf(s);
  if (lane==0) atomicAdd(out, p - logZ);
}

extern "C" void kernel_launch(void* const* d_in, const int* in_sizes, int n_in,
                              void* d_out, int out_size, void* d_ws, size_t ws_size,
                              hipStream_t stream)
{
  const int*   sent  = (const int*)d_in[0];
  const int*   tags  = (const int*)d_in[1];
  const int*   lens  = (const int*)d_in[2];
  const float* emb   = (const float*)d_in[3];
  const float* Wih_f = (const float*)d_in[4];
  const float* Whh_f = (const float*)d_in[5];
  const float* b_f   = (const float*)d_in[6];
  const float* Wih_b = (const float*)d_in[7];
  const float* Whh_b = (const float*)d_in[8];
  const float* b_b   = (const float*)d_in[9];
  const float* Wout  = (const float*)d_in[10];
  const float* bout  = (const float*)d_in[11];
  const float* startv= (const float*)d_in[12];
  const float* endv  = (const float*)d_in[13];
  const float* trans = (const float*)d_in[14];
  char* ws = (char*)d_ws;
  // layout (~171 MB): wihg8 0.5MB | whh4 0.25MB | xw 128MB | hout 32MB | em 2.25MB
  unsigned char* wihg8 = (unsigned char*)(ws);
  unsigned char* whh4  = (unsigned char*)(ws + (size_t)524288);
  unsigned char* xw    = (unsigned char*)(ws + (size_t)1048576);
  unsigned char* hout  = (unsigned char*)(ws + (size_t)135266304);
  float* em            = (float*)(ws + (size_t)168820736);
  float* outp = (float*)d_out;

  (void)hipMemsetAsync(outp, 0, sizeof(float), stream);
  prep_k<<<128, 256, 0, stream>>>(Wih_f, Wih_b, Whh_f, Whh_b, wihg8, whh4);
  xw_gemm_k<<<512, 256, 0, stream>>>(sent, emb, wihg8, lens, b_f, b_b, xw);
  lstm_k<<<64, 512, 0, stream>>>(xw, whh4, lens, hout);
  em_k<<<4096, 256, 0, stream>>>(hout, Wout, bout, lens, em);
  crf_k<<<32, 256, 0, stream>>>(em, tags, lens, startv, endv, trans, outp);
}